// Round 4
// baseline (520.874 us; speedup 1.0000x reference)
//
#include <hip/hip_runtime.h>
#include <stdint.h>

#define EMB 128

typedef unsigned short ushort_t;
typedef ushort_t us8 __attribute__((ext_vector_type(8)));
typedef float f4 __attribute__((ext_vector_type(4)));

static __device__ __forceinline__ float bf2f(ushort_t h) {
    union { unsigned int u; float f; } cvt;
    cvt.u = ((unsigned int)h) << 16;
    return cvt.f;
}

static __device__ __forceinline__ ushort_t f2bf(float f) {
    union { float f; unsigned int u; } cvt;
    cvt.f = f;
    unsigned int u = cvt.u;
    unsigned int r = u + 0x7fffu + ((u >> 16) & 1u);
    return (ushort_t)(r >> 16);
}

// W fp32 [EMB][VOCAB] -> Wt fp32 [VOCAB][EMB]
__global__ __launch_bounds__(256) void transpose_f32_kernel(
    const float* __restrict__ W, float* __restrict__ Wt, int vocab)
{
    __shared__ float tile[32][33];
    const int v0 = blockIdx.x * 32;
    const int e0 = blockIdx.y * 32;
    const int tx = threadIdx.x;
    const int ty = threadIdx.y;

    #pragma unroll
    for (int i = 0; i < 32; i += 8) {
        int e = e0 + ty + i;
        int v = v0 + tx;
        if (e < EMB && v < vocab)
            tile[ty + i][tx] = W[(size_t)e * vocab + v];
    }
    __syncthreads();
    #pragma unroll
    for (int i = 0; i < 32; i += 8) {
        int v = v0 + ty + i;
        int e = e0 + tx;
        if (v < vocab && e < EMB)
            Wt[(size_t)v * EMB + e] = tile[tx][ty + i];
    }
}

// W fp32 [EMB][VOCAB] -> Wt bf16 [VOCAB][EMB]  (fallback for smaller ws)
__global__ __launch_bounds__(256) void transpose_bf16_kernel(
    const float* __restrict__ W, ushort_t* __restrict__ Wt, int vocab)
{
    __shared__ float tile[32][33];
    const int v0 = blockIdx.x * 32;
    const int e0 = blockIdx.y * 32;
    const int tx = threadIdx.x;
    const int ty = threadIdx.y;

    #pragma unroll
    for (int i = 0; i < 32; i += 8) {
        int e = e0 + ty + i;
        int v = v0 + tx;
        if (e < EMB && v < vocab)
            tile[ty + i][tx] = W[(size_t)e * vocab + v];
    }
    __syncthreads();
    #pragma unroll
    for (int i = 0; i < 32; i += 8) {
        int v = v0 + ty + i;
        int e = e0 + tx;
        if (v < vocab && e < EMB)
            Wt[(size_t)v * EMB + e] = f2bf(tile[tx][ty + i]);
    }
}

// Detect int64 vs int32 indices: all high words of first 64 entries zero -> int64.
static __device__ __forceinline__ int detect_i64(const int* __restrict__ x32) {
    __shared__ int is64_s;
    if (threadIdx.x < 64) {
        int w = x32[2 * threadIdx.x + 1];
        unsigned long long nz = __ballot(w != 0);
        if (threadIdx.x == 0) is64_s = (nz == 0ULL) ? 1 : 0;
    }
    __syncthreads();
    return is64_s;
}

static __device__ __forceinline__ void reduce_norm_store(
    float e[8], float* __restrict__ out, int token, int l)
{
    float ss = 0.0f;
    #pragma unroll
    for (int j = 0; j < 8; ++j) ss += e[j] * e[j];
    #pragma unroll
    for (int m = 1; m < 16; m <<= 1)
        ss += __shfl_xor(ss, m, 16);
    const float n = sqrtf(ss);
    const float scale = 1.0f / fmaxf(n, 1e-12f);

    f4 o0, o1;
    #pragma unroll
    for (int j = 0; j < 4; ++j) { o0[j] = e[j] * scale; o1[j] = e[j + 4] * scale; }
    float* dst = out + (size_t)token * EMB + l * 8;
    *(f4*)dst = o0;
    *(f4*)(dst + 4) = o1;
}

// 16 lanes per token; fp32 Wt rows
__global__ __launch_bounds__(256) void gather_norm_f32_kernel(
    const int* __restrict__ x, const float* __restrict__ Wt,
    const float* __restrict__ b, float* __restrict__ out,
    int n_tokens, int vocab)
{
    const int is64 = detect_i64(x);
    const int tid   = blockIdx.x * blockDim.x + threadIdx.x;
    const int token = tid >> 4;
    const int l     = tid & 15;
    if (token >= n_tokens) return;

    int v = is64 ? x[2 * token] : x[token];
    v = min(max(v, 0), vocab - 1);

    const float* row = Wt + (size_t)v * EMB + l * 8;
    f4 w0 = *(const f4*)row;
    f4 w1 = *(const f4*)(row + 4);
    f4 b0 = *(const f4*)(b + l * 8);
    f4 b1 = *(const f4*)(b + l * 8 + 4);

    float e[8];
    #pragma unroll
    for (int j = 0; j < 4; ++j) { e[j] = w0[j] + b0[j]; e[j + 4] = w1[j] + b1[j]; }
    reduce_norm_store(e, out, token, l);
}

// 16 lanes per token; bf16 Wt rows
__global__ __launch_bounds__(256) void gather_norm_bf16_kernel(
    const int* __restrict__ x, const ushort_t* __restrict__ Wt,
    const float* __restrict__ b, float* __restrict__ out,
    int n_tokens, int vocab)
{
    const int is64 = detect_i64(x);
    const int tid   = blockIdx.x * blockDim.x + threadIdx.x;
    const int token = tid >> 4;
    const int l     = tid & 15;
    if (token >= n_tokens) return;

    int v = is64 ? x[2 * token] : x[token];
    v = min(max(v, 0), vocab - 1);

    us8 w  = *(const us8*)(Wt + (size_t)v * EMB + l * 8);
    f4 b0  = *(const f4*)(b + l * 8);
    f4 b1  = *(const f4*)(b + l * 8 + 4);

    float e[8];
    #pragma unroll
    for (int j = 0; j < 4; ++j) {
        e[j]     = bf2f(w[j])     + b0[j];
        e[j + 4] = bf2f(w[j + 4]) + b1[j];
    }
    reduce_norm_store(e, out, token, l);
}

// last-resort: gather directly from fp32 W columns (uncoalesced)
__global__ __launch_bounds__(256) void gather_norm_direct_kernel(
    const int* __restrict__ x, const float* __restrict__ W,
    const float* __restrict__ b, float* __restrict__ out,
    int n_tokens, int vocab)
{
    const int is64 = detect_i64(x);
    const int tid   = blockIdx.x * blockDim.x + threadIdx.x;
    const int token = tid >> 4;
    const int l     = tid & 15;
    if (token >= n_tokens) return;

    int v = is64 ? x[2 * token] : x[token];
    v = min(max(v, 0), vocab - 1);

    f4 b0 = *(const f4*)(b + l * 8);
    f4 b1 = *(const f4*)(b + l * 8 + 4);

    float e[8];
    #pragma unroll
    for (int j = 0; j < 8; ++j) {
        float w = W[(size_t)(l * 8 + j) * vocab + v];
        float bj = (j < 4) ? b0[j & 3] : b1[j & 3];
        e[j] = w + bj;
    }
    reduce_norm_store(e, out, token, l);
}

extern "C" void kernel_launch(void* const* d_in, const int* in_sizes, int n_in,
                              void* d_out, int out_size, void* d_ws, size_t ws_size,
                              hipStream_t stream) {
    const int*   x = (const int*)d_in[0];
    const float* W = (const float*)d_in[1];
    const float* b = (const float*)d_in[2];
    float*     out = (float*)d_out;

    const int n_tokens = in_sizes[0];            // 4096*200 = 819200
    const int vocab    = in_sizes[1] / EMB;      // 100000

    const size_t wt_f32_bytes  = (size_t)vocab * EMB * sizeof(float);     // 51.2 MB
    const size_t wt_bf16_bytes = (size_t)vocab * EMB * sizeof(ushort_t);  // 25.6 MB
    const int blocks = (n_tokens * 16 + 255) / 256;                       // 16 lanes/token

    dim3 tb(32, 8);
    dim3 tg((vocab + 31) / 32, (EMB + 31) / 32);

    if (ws_size >= wt_f32_bytes) {
        float* Wt = (float*)d_ws;
        transpose_f32_kernel<<<tg, tb, 0, stream>>>(W, Wt, vocab);
        gather_norm_f32_kernel<<<blocks, 256, 0, stream>>>(x, Wt, b, out, n_tokens, vocab);
    } else if (ws_size >= wt_bf16_bytes) {
        ushort_t* Wt = (ushort_t*)d_ws;
        transpose_bf16_kernel<<<tg, tb, 0, stream>>>(W, Wt, vocab);
        gather_norm_bf16_kernel<<<blocks, 256, 0, stream>>>(x, Wt, b, out, n_tokens, vocab);
    } else {
        gather_norm_direct_kernel<<<blocks, 256, 0, stream>>>(x, W, b, out, n_tokens, vocab);
    }
}